// Round 12
// baseline (98.331 us; speedup 1.0000x reference)
//
#include <hip/hip_runtime.h>
#include <hip/hip_bf16.h>
#include <math.h>

typedef __attribute__((ext_vector_type(8))) short short8;
typedef __attribute__((ext_vector_type(4))) float f32x4;
typedef __attribute__((ext_vector_type(4))) unsigned short us4;
typedef __attribute__((ext_vector_type(2))) unsigned int u32x2;

#define DM 1024
#define NH 16
#define DH 64
#define SS 1024
#define C2 0.180336879f   /* 0.125 * log2(e) */

#define GLDS16(g, l) __builtin_amdgcn_global_load_lds(                      \
    (const __attribute__((address_space(1))) unsigned int*)(g),             \
    (__attribute__((address_space(3))) unsigned int*)(l), 16, 0, 0)

__device__ __forceinline__ unsigned short f2b(float f){
    unsigned int u = __float_as_uint(f);
    u += 0x7fffu + ((u >> 16) & 1u);
    return (unsigned short)(u >> 16);
}
__device__ __forceinline__ float b2f(unsigned short b){
    return __uint_as_float(((unsigned int)b) << 16);
}
__device__ __forceinline__ unsigned int cvt_pk_bf16(float lo, float hi){
    unsigned int r;
    asm volatile("v_cvt_pk_bf16_f32 %0, %1, %2" : "=v"(r) : "v"(lo), "v"(hi));
    return r;
}

// ---- cast fp32 -> bf16, 4 elems/thread ----
__global__ __launch_bounds__(256) void cast_f32_bf16_k(const float* __restrict__ in,
                                                       unsigned short* __restrict__ out){
    int i = (blockIdx.x * 256 + threadIdx.x) * 4;
    float4 v = *(const float4*)(in + i);
    us4 o = { f2b(v.x), f2b(v.y), f2b(v.z), f2b(v.w) };
    *(us4*)(out + i) = o;
}

// ---- transpose + cast W -> wT[proj*1024 + o][k] (bf16) ----
__global__ __launch_bounds__(256) void transpose_cast_w_k(const float* __restrict__ Wq,
                                                          const float* __restrict__ Wk,
                                                          const float* __restrict__ Wv,
                                                          unsigned short* __restrict__ wT){
    __shared__ float tile[32][33];
    const float* W = blockIdx.z==0 ? Wq : (blockIdx.z==1 ? Wk : Wv);
    int o0 = blockIdx.x*32, k0 = blockIdx.y*32;
    int tx = threadIdx.x, ty = threadIdx.y;
    #pragma unroll
    for (int i=0;i<32;i+=8) tile[ty+i][tx] = W[(k0+ty+i)*DM + o0+tx];
    __syncthreads();
    #pragma unroll
    for (int i=0;i<32;i+=8) wT[(blockIdx.z*DM + o0+ty+i)*DM + k0+tx] = f2b(tile[tx][ty+i]);
}

// ---- Q/K GEMM: BK=64, XOR-swizzled LDS (r8 proven body) ----
__global__ __launch_bounds__(256) void gemm_qk_k(
    const unsigned short* __restrict__ xb, const unsigned short* __restrict__ wT,
    const float* __restrict__ bq, const float* __restrict__ bk,
    unsigned short* __restrict__ Qb, unsigned short* __restrict__ Kb)
{
    __shared__ unsigned short lda[128*64];
    __shared__ unsigned short ldb[128*64];
    const int tid = threadIdx.x;
    const int lane = tid & 63, w = tid >> 6;
    const int wr = w >> 1, wc = w & 1;
    const int lr = lane & 15, lk4 = lane >> 4;
    const int m0 = blockIdx.y * 128, n0 = blockIdx.x * 128;   // n0 in [0,2048)
    f32x4 acc[4][4] = {};
    for (int k0 = 0; k0 < DM; k0 += 64){
        #pragma unroll
        for (int p=0;p<4;p++){
            int idx = tid + p*256;
            int row = idx >> 3, ch = idx & 7;
            GLDS16(&xb[(m0+row)*DM + k0 + ((ch ^ (row&7))<<3)], &lda[idx<<3]);
            GLDS16(&wT[(n0+row)*DM + k0 + ((ch ^ (row&7))<<3)], &ldb[idx<<3]);
        }
        __syncthreads();
        #pragma unroll
        for (int kk=0;kk<2;kk++){
            const int sco = ((kk*4+lk4) ^ (lr&7)) << 3;
            short8 a[4], b[4];
            #pragma unroll
            for (int m=0;m<4;m++) a[m] = *(const short8*)(&lda[(wr*64+m*16+lr)*64 + sco]);
            #pragma unroll
            for (int n=0;n<4;n++) b[n] = *(const short8*)(&ldb[(wc*64+n*16+lr)*64 + sco]);
            __builtin_amdgcn_s_setprio(1);
            #pragma unroll
            for (int m=0;m<4;m++)
                #pragma unroll
                for (int n=0;n<4;n++)
                    acc[m][n] = __builtin_amdgcn_mfma_f32_16x16x32_bf16(a[m], b[n], acc[m][n], 0,0,0);
            __builtin_amdgcn_s_setprio(0);
        }
        __syncthreads();
    }
    #pragma unroll
    for (int m=0;m<4;m++){
        #pragma unroll
        for (int n=0;n<4;n++){
            int C = n0 + wc*64 + n*16 + lr;
            int proj = C >> 10, hd = C & 1023;          // proj in {0,1}
            float badd = (proj==0 ? bq : bk)[hd];
            int h = hd >> 6, d = hd & 63;
            #pragma unroll
            for (int r=0;r<4;r++){
                int R = m0 + wr*64 + m*16 + lk4*4 + r;
                int b_ = R >> 10, s = R & 1023;
                float v = acc[m][n][r] + badd;
                (proj==0 ? Qb : Kb)[(((b_*NH)+h)*SS + s)*DH + d] = f2b(proj==0 ? v*C2 : v);
            }
        }
    }
}

// ---- V GEMM, swapped operands: D[o][s] = w_o . x_s  ->  writes V^T [bh][d][s] directly ----
__global__ __launch_bounds__(256) void gemm_vt_k(
    const unsigned short* __restrict__ xb, const unsigned short* __restrict__ wTv,
    const float* __restrict__ bv, unsigned short* __restrict__ VTb)
{
    __shared__ unsigned short lda[128*64];   // wTv rows (o)
    __shared__ unsigned short ldb[128*64];   // xb rows (s)
    const int tid = threadIdx.x;
    const int lane = tid & 63, w = tid >> 6;
    const int wr = w >> 1, wc = w & 1;
    const int lr = lane & 15, lk4 = lane >> 4;
    const int o0 = blockIdx.x * 128;         // 8 blocks
    const int s0 = blockIdx.y * 128;         // 32 blocks
    f32x4 acc[4][4] = {};
    for (int k0 = 0; k0 < DM; k0 += 64){
        #pragma unroll
        for (int p=0;p<4;p++){
            int idx = tid + p*256;
            int row = idx >> 3, ch = idx & 7;
            GLDS16(&wTv[(o0+row)*DM + k0 + ((ch ^ (row&7))<<3)], &lda[idx<<3]);
            GLDS16(&xb[(s0+row)*DM + k0 + ((ch ^ (row&7))<<3)], &ldb[idx<<3]);
        }
        __syncthreads();
        #pragma unroll
        for (int kk=0;kk<2;kk++){
            const int sco = ((kk*4+lk4) ^ (lr&7)) << 3;
            short8 a[4], b[4];
            #pragma unroll
            for (int m=0;m<4;m++) a[m] = *(const short8*)(&lda[(wr*64+m*16+lr)*64 + sco]);
            #pragma unroll
            for (int n=0;n<4;n++) b[n] = *(const short8*)(&ldb[(wc*64+n*16+lr)*64 + sco]);
            __builtin_amdgcn_s_setprio(1);
            #pragma unroll
            for (int m=0;m<4;m++)
                #pragma unroll
                for (int n=0;n<4;n++)
                    acc[m][n] = __builtin_amdgcn_mfma_f32_16x16x32_bf16(a[m], b[n], acc[m][n], 0,0,0);
            __builtin_amdgcn_s_setprio(0);
        }
        __syncthreads();
    }
    // frag: col (lane&15) = s-local, row (lk4*4+r) = o-local
    #pragma unroll
    for (int m=0;m<4;m++){
        #pragma unroll
        for (int n=0;n<4;n++){
            int sg = s0 + wc*64 + n*16 + lr;
            int b_ = sg >> 10, s = sg & 1023;
            #pragma unroll
            for (int r=0;r<4;r++){
                int o = o0 + wr*64 + m*16 + lk4*4 + r;
                int h = o >> 6, d = o & 63;
                VTb[(((b_*NH)+h)*DH + d)*SS + s] = f2b(acc[m][n][r] + bv[o]);
            }
        }
    }
}

// ---- fused relative attention: QBLK=64, 4 waves, paired segments, Er ring staging ----
__global__ __launch_bounds__(256) void attn_k(
    const unsigned short* __restrict__ Qb, const unsigned short* __restrict__ Kb,
    const unsigned short* __restrict__ VTb, const unsigned short* __restrict__ Erb,
    float* __restrict__ out)
{
    __shared__ unsigned short k_lds[64*64];     //  8 KB
    __shared__ unsigned short vt_lds[64*64];    //  8 KB
    __shared__ unsigned short er_lds[128*64];   // 16 KB  (ring of 128 rows)
    __shared__ unsigned short p_lds[64*64];     //  8 KB
    __shared__ unsigned short rbt[4][80*20];    // 12.5 KB

    const int tid = threadIdx.x, lane = tid & 63, w = tid >> 6;   // w in [0,4)
    const int lr = lane & 15, lk4 = lane >> 4;
    const int bh = blockIdx.x;
    const int pr = blockIdx.y;                                    // pair 0..7
    const unsigned short* q_b  = Qb  + bh*SS*DH;
    const unsigned short* k_b  = Kb  + bh*SS*DH;
    const unsigned short* vt_b = VTb + bh*DH*SS;

    auto STAGE_K = [&](int j0){
        #pragma unroll
        for (int p=0;p<2;p++){
            int idx = tid + p*256;
            int row = idx >> 3, ch = idx & 7;
            GLDS16(&k_b[(j0+row)*DH + ((ch ^ (row&7))<<3)], &k_lds[idx<<3]);
        }
    };
    auto STAGE_VT = [&](int j0){
        #pragma unroll
        for (int p=0;p<2;p++){
            int idx = tid + p*256;
            int row = idx >> 3, ch = idx & 7;
            GLDS16(&vt_b[row*SS + j0 + ((ch ^ (row&7))<<3)], &vt_lds[idx<<3]);
        }
    };
    auto STAGE_ER_FULL = [&](int t0){               // phys = logical
        #pragma unroll
        for (int p=0;p<4;p++){
            int idx = tid + p*256;
            int row = idx >> 3, ch = idx & 7;
            GLDS16(&Erb[(t0+row)*DH + ((ch ^ (row&7))<<3)], &er_lds[idx<<3]);
        }
    };
    auto STAGE_ER_HALF = [&](int absbase, int rof){ // 64 new rows at phys q+rof
        #pragma unroll
        for (int p=0;p<2;p++){
            int idx = tid + p*256;                  // 0..511
            int q = idx >> 3, ch = idx & 7;
            GLDS16(&Erb[(absbase+q)*DH + ((ch ^ (q&7))<<3)],
                   &er_lds[((((q+rof)<<3) + ch))<<3]);
        }
    };

    unsigned short* rbw = &rbt[w][0];
    const int fbase = 3 - w;

    for (int seg=0; seg<2; ++seg){
        const int ib = seg ? 15 - pr : pr;
        const int i0 = ib * 64;
        const int ntiles = ib + 1;
        const int t0s = 960 - i0;                   // band(t) base = t0s + j0

        STAGE_K(0);
        STAGE_ER_FULL(t0s);

        short8 qf[2];
        #pragma unroll
        for (int kk=0;kk<2;kk++)
            qf[kk] = *(const short8*)(&q_b[(i0 + w*16 + lr)*DH + kk*32 + lk4*8]);

        __syncthreads();   // K(0), Er(0) landed; prev-seg LDS readers done

        f32x4 o_acc[4] = {};
        float l_r[4] = {0.f,0.f,0.f,0.f};

        for (int t=0; t<ntiles; t++){
            const int j0 = t*64;
            const int rof = (t & 1) * 64;           // ring offset of current band
            STAGE_VT(j0);                           // lands by mid-barrier

            f32x4 s_acc[4] = {};
            f32x4 r_acc[5] = {};
            __builtin_amdgcn_s_setprio(1);
            #pragma unroll
            for (int kk=0;kk<2;kk++){
                const int sco = ((kk*4+lk4) ^ (lr&7)) << 3;
                #pragma unroll
                for (int n=0;n<4;n++){
                    short8 kf = *(const short8*)(&k_lds[(n*16+lr)*64 + sco]);
                    s_acc[n] = __builtin_amdgcn_mfma_f32_16x16x32_bf16(qf[kk], kf, s_acc[n], 0,0,0);
                }
                #pragma unroll
                for (int fi=0;fi<5;fi++){
                    const int ero = (((fbase+fi)*16+lr) + rof) & 127;
                    short8 ef = *(const short8*)(&er_lds[ero*64 + sco]);
                    r_acc[fi] = __builtin_amdgcn_mfma_f32_16x16x32_bf16(qf[kk], ef, r_acc[fi], 0,0,0);
                }
            }
            __builtin_amdgcn_s_setprio(0);

            __syncthreads();                        // K/Er readers done; VT(t) landed
            if (t+1 < ntiles){
                STAGE_K(j0+64);                     // land under softmax+PV
                STAGE_ER_HALF(t0s + j0 + 128, rof); // 64 new band rows into expired slots
            }

            // spill R (wave-private column stripe, b64 writes)
            #pragma unroll
            for (int fi=0;fi<5;fi++){
                u32x2 pk;
                pk[0] = cvt_pk_bf16(r_acc[fi][0], r_acc[fi][1]);
                pk[1] = cvt_pk_bf16(r_acc[fi][2], r_acc[fi][3]);
                *(u32x2*)(&rbw[(fi*16+lr)*20 + lk4*4]) = pk;
            }

            // fixed-shift softmax
            float s2[4][4];
            #pragma unroll
            for (int r=0;r<4;r++){
                const int rr = lk4*4 + r;
                const int gb = (15 - rr + lr)*20 + rr;
                #pragma unroll
                for (int n=0;n<4;n++)
                    s2[n][r] = s_acc[n][r] + b2f(rbw[gb + n*320]);
            }
            if (t == ntiles-1){
                #pragma unroll
                for (int r=0;r<4;r++){
                    const int gi = i0 + w*16 + lk4*4 + r;
                    #pragma unroll
                    for (int n=0;n<4;n++)
                        if (j0 + n*16 + lr > gi) s2[n][r] = -INFINITY;
                }
            }
            #pragma unroll
            for (int r=0;r<4;r++){
                float p0 = __builtin_amdgcn_exp2f(s2[0][r]);
                float p1 = __builtin_amdgcn_exp2f(s2[1][r]);
                float p2 = __builtin_amdgcn_exp2f(s2[2][r]);
                float p3 = __builtin_amdgcn_exp2f(s2[3][r]);
                l_r[r] += (p0+p1)+(p2+p3);
                unsigned int u01 = cvt_pk_bf16(p0, p1);
                unsigned int u23 = cvt_pk_bf16(p2, p3);
                const int li = w*16 + lk4*4 + r;
                const int ro = li*64 + (lr&7);
                p_lds[ro + (((0 + (lr>>3)) ^ (li&7))<<3)] = (unsigned short)u01;
                p_lds[ro + (((2 + (lr>>3)) ^ (li&7))<<3)] = (unsigned short)(u01>>16);
                p_lds[ro + (((4 + (lr>>3)) ^ (li&7))<<3)] = (unsigned short)u23;
                p_lds[ro + (((6 + (lr>>3)) ^ (li&7))<<3)] = (unsigned short)(u23>>16);
            }

            // O += P V
            __builtin_amdgcn_s_setprio(1);
            #pragma unroll
            for (int kk=0;kk<2;kk++){
                const int sco = ((kk*4+lk4) ^ (lr&7)) << 3;
                short8 pf = *(const short8*)(&p_lds[(w*16+lr)*64 + sco]);
                #pragma unroll
                for (int n=0;n<4;n++){
                    short8 vf = *(const short8*)(&vt_lds[(n*16+lr)*64 + sco]);
                    o_acc[n] = __builtin_amdgcn_mfma_f32_16x16x32_bf16(pf, vf, o_acc[n], 0,0,0);
                }
            }
            __builtin_amdgcn_s_setprio(0);
            __syncthreads();                        // drains K/Er(t+1); VT/p readers done
        }

        // segment epilogue
        #pragma unroll
        for (int r=0;r<4;r++){
            float l = l_r[r];
            #pragma unroll
            for (int msk=1; msk<16; msk<<=1) l += __shfl_xor(l, msk);
            l_r[r] = 1.0f / l;
        }
        const int b_ = bh >> 4, h = bh & 15;
        #pragma unroll
        for (int n=0;n<4;n++)
            #pragma unroll
            for (int r=0;r<4;r++){
                int li = w*16 + lk4*4 + r;
                int d = n*16 + lr;
                out[(b_*SS + i0 + li)*DM + h*DH + d] = o_acc[n][r] * l_r[r];
            }
    }
}

extern "C" void kernel_launch(void* const* d_in, const int* in_sizes, int n_in,
                              void* d_out, int out_size, void* d_ws, size_t ws_size,
                              hipStream_t stream)
{
    const float* x  = (const float*)d_in[0];
    const float* Wq = (const float*)d_in[1];
    const float* bq = (const float*)d_in[2];
    const float* Wk = (const float*)d_in[3];
    const float* bk = (const float*)d_in[4];
    const float* Wv = (const float*)d_in[5];
    const float* bv = (const float*)d_in[6];
    const float* Er = (const float*)d_in[7];
    float* out = (float*)d_out;
    char* ws = (char*)d_ws;
    unsigned short* xb  = (unsigned short*)(ws);              // 8 MB   x bf16 [4096][1024]
    unsigned short* wT  = (unsigned short*)(ws + 8388608);    // 6 MB   W^T bf16 [3072][1024]
    unsigned short* erb = (unsigned short*)(ws + 14680064);   // 144 KB Er bf16 [1152][64] (128 zero rows)
    unsigned short* Qb  = (unsigned short*)(ws + 14827520);   // 8 MB   Q bf16 [bh][s][d] (pre-scaled C2)
    unsigned short* Kb  = (unsigned short*)(ws + 23216128);   // 8 MB   K bf16 [bh][s][d]
    unsigned short* VTb = (unsigned short*)(ws + 31604736);   // 8 MB   V^T bf16 [bh][d][s] (written by gemm_vt)

    cast_f32_bf16_k<<<4096, 256, 0, stream>>>(x, xb);
    cast_f32_bf16_k<<<64, 256, 0, stream>>>(Er, erb);
    hipMemsetAsync(erb + 1024*DH, 0, 128*DH*sizeof(unsigned short), stream);
    transpose_cast_w_k<<<dim3(32,32,3), dim3(32,8), 0, stream>>>(Wq, Wk, Wv, wT);
    gemm_qk_k<<<dim3(16,32), 256, 0, stream>>>(xb, wT, bq, bk, Qb, Kb);
    gemm_vt_k<<<dim3(8,32), 256, 0, stream>>>(xb, wT + 2048*DM, bv, VTb);
    attn_k<<<dim3(64,8), 256, 0, stream>>>(Qb, Kb, VTb, erb, out);
}

// Round 16
// 89.411 us; speedup vs baseline: 1.0998x; 1.0998x over previous
//
#include <hip/hip_runtime.h>
#include <hip/hip_bf16.h>
#include <math.h>

typedef __attribute__((ext_vector_type(8))) short short8;
typedef __attribute__((ext_vector_type(4))) float f32x4;
typedef __attribute__((ext_vector_type(4))) unsigned short us4;
typedef __attribute__((ext_vector_type(2))) unsigned int u32x2;

#define DM 1024
#define NH 16
#define DH 64
#define SS 1024
#define C2 0.180336879f   /* 0.125 * log2(e) */

#define GLDS16(g, l) __builtin_amdgcn_global_load_lds(                      \
    (const __attribute__((address_space(1))) unsigned int*)(g),             \
    (__attribute__((address_space(3))) unsigned int*)(l), 16, 0, 0)

__device__ __forceinline__ unsigned short f2b(float f){
    unsigned int u = __float_as_uint(f);
    u += 0x7fffu + ((u >> 16) & 1u);
    return (unsigned short)(u >> 16);
}
__device__ __forceinline__ float b2f(unsigned short b){
    return __uint_as_float(((unsigned int)b) << 16);
}
__device__ __forceinline__ unsigned int cvt_pk_bf16(float lo, float hi){
    unsigned int r;
    asm volatile("v_cvt_pk_bf16_f32 %0, %1, %2" : "=v"(r) : "v"(lo), "v"(hi));
    return r;
}

// ---- cast fp32 -> bf16, 4 elems/thread ----
__global__ __launch_bounds__(256) void cast_f32_bf16_k(const float* __restrict__ in,
                                                       unsigned short* __restrict__ out){
    int i = (blockIdx.x * 256 + threadIdx.x) * 4;
    float4 v = *(const float4*)(in + i);
    us4 o = { f2b(v.x), f2b(v.y), f2b(v.z), f2b(v.w) };
    *(us4*)(out + i) = o;
}

// ---- transpose + cast W -> wT[proj*1024 + o][k] (bf16) ----
__global__ __launch_bounds__(256) void transpose_cast_w_k(const float* __restrict__ Wq,
                                                          const float* __restrict__ Wk,
                                                          const float* __restrict__ Wv,
                                                          unsigned short* __restrict__ wT){
    __shared__ float tile[32][33];
    const float* W = blockIdx.z==0 ? Wq : (blockIdx.z==1 ? Wk : Wv);
    int o0 = blockIdx.x*32, k0 = blockIdx.y*32;
    int tx = threadIdx.x, ty = threadIdx.y;
    #pragma unroll
    for (int i=0;i<32;i+=8) tile[ty+i][tx] = W[(k0+ty+i)*DM + o0+tx];
    __syncthreads();
    #pragma unroll
    for (int i=0;i<32;i+=8) wT[(blockIdx.z*DM + o0+ty+i)*DM + k0+tx] = f2b(tile[tx][ty+i]);
}

// ---- QKV GEMM: BK=64, XOR-swizzled LDS, half the barriers (r8/r11 proven) ----
__global__ __launch_bounds__(256) void gemm_qkv_k(
    const unsigned short* __restrict__ xb, const unsigned short* __restrict__ wT,
    const float* __restrict__ bq, const float* __restrict__ bk, const float* __restrict__ bv,
    unsigned short* __restrict__ Qb, unsigned short* __restrict__ Kb, unsigned short* __restrict__ Vb)
{
    __shared__ unsigned short lda[128*64];   // 16 KB, [row][chunk ^ (row&7)]
    __shared__ unsigned short ldb[128*64];   // 16 KB
    const int tid = threadIdx.x;
    const int lane = tid & 63, w = tid >> 6;
    const int wr = w >> 1, wc = w & 1;
    const int lr = lane & 15, lk4 = lane >> 4;
    const int m0 = blockIdx.y * 128, n0 = blockIdx.x * 128;
    f32x4 acc[4][4] = {};
    for (int k0 = 0; k0 < DM; k0 += 64){
        #pragma unroll
        for (int p=0;p<4;p++){
            int idx = tid + p*256;              // 0..1023
            int row = idx >> 3, ch = idx & 7;
            GLDS16(&xb[(m0+row)*DM + k0 + ((ch ^ (row&7))<<3)], &lda[idx<<3]);
            GLDS16(&wT[(n0+row)*DM + k0 + ((ch ^ (row&7))<<3)], &ldb[idx<<3]);
        }
        __syncthreads();
        #pragma unroll
        for (int kk=0;kk<2;kk++){
            const int sco = ((kk*4+lk4) ^ (lr&7)) << 3;
            short8 a[4], b[4];
            #pragma unroll
            for (int m=0;m<4;m++) a[m] = *(const short8*)(&lda[(wr*64+m*16+lr)*64 + sco]);
            #pragma unroll
            for (int n=0;n<4;n++) b[n] = *(const short8*)(&ldb[(wc*64+n*16+lr)*64 + sco]);
            __builtin_amdgcn_s_setprio(1);
            #pragma unroll
            for (int m=0;m<4;m++)
                #pragma unroll
                for (int n=0;n<4;n++)
                    acc[m][n] = __builtin_amdgcn_mfma_f32_16x16x32_bf16(a[m], b[n], acc[m][n], 0,0,0);
            __builtin_amdgcn_s_setprio(0);
        }
        __syncthreads();
    }
    #pragma unroll
    for (int m=0;m<4;m++){
        #pragma unroll
        for (int n=0;n<4;n++){
            int C = n0 + wc*64 + n*16 + lr;
            int proj = C >> 10, hd = C & 1023;
            const float* bias = proj==0 ? bq : (proj==1 ? bk : bv);
            float badd = bias[hd];
            int h = hd >> 6, d = hd & 63;
            #pragma unroll
            for (int r=0;r<4;r++){
                int R = m0 + wr*64 + m*16 + lk4*4 + r;
                int b_ = R >> 10, s = R & 1023;
                float v = acc[m][n][r] + badd;
                unsigned short val = f2b(proj==0 ? v*C2 : v);
                unsigned short* dst = proj==0 ? Qb : (proj==1 ? Kb : Vb);
                dst[(((b_*NH)+h)*SS + s)*DH + d] = val;
            }
        }
    }
}

// ---- V [bh][s][d] -> V^T [bh][d][s] via padded-LDS 64x64 tile ----
__global__ __launch_bounds__(256) void transpose_v_k(const unsigned short* __restrict__ Vb,
                                                     unsigned short* __restrict__ VTb){
    __shared__ unsigned short t[64*72];
    const int tid = threadIdx.x;
    const int bh = blockIdx.x, s0 = blockIdx.y * 64;
    const int s = tid & 63, d0 = (tid >> 6) * 16;
    const unsigned short* src = Vb + (bh*SS + s0 + s)*DH;
    short8 v0 = *(const short8*)(src + d0);
    short8 v1 = *(const short8*)(src + d0 + 8);
    #pragma unroll
    for (int e=0;e<8;e++){
        t[(d0+e)*72 + s]   = (unsigned short)v0[e];
        t[(d0+8+e)*72 + s] = (unsigned short)v1[e];
    }
    __syncthreads();
    unsigned short* dst = VTb + bh*DH*SS + s0;
    #pragma unroll
    for (int q=0;q<2;q++){
        int idx = q*256 + tid;
        int d = idx >> 3, sc = idx & 7;
        short8 o = *(const short8*)(&t[d*72 + sc*8]);
        *(short8*)(dst + d*SS + sc*8) = o;
    }
}

// ---- fused relative attention: QBLK=64, 4 waves, paired segments, Er ring staging (r12) ----
__global__ __launch_bounds__(256) void attn_k(
    const unsigned short* __restrict__ Qb, const unsigned short* __restrict__ Kb,
    const unsigned short* __restrict__ VTb, const unsigned short* __restrict__ Erb,
    float* __restrict__ out)
{
    __shared__ unsigned short k_lds[64*64];     //  8 KB
    __shared__ unsigned short vt_lds[64*64];    //  8 KB
    __shared__ unsigned short er_lds[128*64];   // 16 KB  (ring of 128 rows)
    __shared__ unsigned short p_lds[64*64];     //  8 KB
    __shared__ unsigned short rbt[4][80*20];    // 12.5 KB  (total 52.5 KB -> 3 blocks/CU)

    const int tid = threadIdx.x, lane = tid & 63, w = tid >> 6;   // w in [0,4)
    const int lr = lane & 15, lk4 = lane >> 4;
    const int bh = blockIdx.x;
    const int pr = blockIdx.y;                                    // pair 0..7
    const unsigned short* q_b  = Qb  + bh*SS*DH;
    const unsigned short* k_b  = Kb  + bh*SS*DH;
    const unsigned short* vt_b = VTb + bh*DH*SS;

    auto STAGE_K = [&](int j0){
        #pragma unroll
        for (int p=0;p<2;p++){
            int idx = tid + p*256;
            int row = idx >> 3, ch = idx & 7;
            GLDS16(&k_b[(j0+row)*DH + ((ch ^ (row&7))<<3)], &k_lds[idx<<3]);
        }
    };
    auto STAGE_VT = [&](int j0){
        #pragma unroll
        for (int p=0;p<2;p++){
            int idx = tid + p*256;
            int row = idx >> 3, ch = idx & 7;
            GLDS16(&vt_b[row*SS + j0 + ((ch ^ (row&7))<<3)], &vt_lds[idx<<3]);
        }
    };
    auto STAGE_ER_FULL = [&](int t0){               // phys = logical
        #pragma unroll
        for (int p=0;p<4;p++){
            int idx = tid + p*256;
            int row = idx >> 3, ch = idx & 7;
            GLDS16(&Erb[(t0+row)*DH + ((ch ^ (row&7))<<3)], &er_lds[idx<<3]);
        }
    };
    auto STAGE_ER_HALF = [&](int absbase, int rof){ // 64 new rows at phys q+rof
        #pragma unroll
        for (int p=0;p<2;p++){
            int idx = tid + p*256;                  // 0..511
            int q = idx >> 3, ch = idx & 7;
            GLDS16(&Erb[(absbase+q)*DH + ((ch ^ (q&7))<<3)],
                   &er_lds[((((q+rof)<<3) + ch))<<3]);
        }
    };

    unsigned short* rbw = &rbt[w][0];
    const int fbase = 3 - w;

    for (int seg=0; seg<2; ++seg){
        const int ib = seg ? 15 - pr : pr;
        const int i0 = ib * 64;
        const int ntiles = ib + 1;
        const int t0s = 960 - i0;                   // band(t) base = t0s + j0

        STAGE_K(0);
        STAGE_ER_FULL(t0s);

        short8 qf[2];
        #pragma unroll
        for (int kk=0;kk<2;kk++)
            qf[kk] = *(const short8*)(&q_b[(i0 + w*16 + lr)*DH + kk*32 + lk4*8]);

        __syncthreads();   // K(0), Er(0) landed; prev-seg LDS readers done

        f32x4 o_acc[4] = {};
        float l_r[4] = {0.f,0.f,0.f,0.f};

        for (int t=0; t<ntiles; t++){
            const int j0 = t*64;
            const int rof = (t & 1) * 64;           // ring offset of current band
            STAGE_VT(j0);                           // lands by mid-barrier

            f32x4 s_acc[4] = {};
            f32x4 r_acc[5] = {};
            __builtin_amdgcn_s_setprio(1);
            #pragma unroll
            for (int kk=0;kk<2;kk++){
                const int sco = ((kk*4+lk4) ^ (lr&7)) << 3;
                #pragma unroll
                for (int n=0;n<4;n++){
                    short8 kf = *(const short8*)(&k_lds[(n*16+lr)*64 + sco]);
                    s_acc[n] = __builtin_amdgcn_mfma_f32_16x16x32_bf16(qf[kk], kf, s_acc[n], 0,0,0);
                }
                #pragma unroll
                for (int fi=0;fi<5;fi++){
                    const int ero = (((fbase+fi)*16+lr) + rof) & 127;
                    short8 ef = *(const short8*)(&er_lds[ero*64 + sco]);
                    r_acc[fi] = __builtin_amdgcn_mfma_f32_16x16x32_bf16(qf[kk], ef, r_acc[fi], 0,0,0);
                }
            }
            __builtin_amdgcn_s_setprio(0);

            __syncthreads();                        // K/Er readers done; VT(t) landed
            if (t+1 < ntiles){
                STAGE_K(j0+64);                     // land under softmax+PV
                STAGE_ER_HALF(t0s + j0 + 128, rof); // 64 new band rows into expired slots
            }

            // spill R (wave-private column stripe, b64 writes)
            #pragma unroll
            for (int fi=0;fi<5;fi++){
                u32x2 pk;
                pk[0] = cvt_pk_bf16(r_acc[fi][0], r_acc[fi][1]);
                pk[1] = cvt_pk_bf16(r_acc[fi][2], r_acc[fi][3]);
                *(u32x2*)(&rbw[(fi*16+lr)*20 + lk4*4]) = pk;
            }

            // fixed-shift softmax
            float s2[4][4];
            #pragma unroll
            for (int r=0;r<4;r++){
                const int rr = lk4*4 + r;
                const int gb = (15 - rr + lr)*20 + rr;
                #pragma unroll
                for (int n=0;n<4;n++)
                    s2[n][r] = s_acc[n][r] + b2f(rbw[gb + n*320]);
            }
            if (t == ntiles-1){
                #pragma unroll
                for (int r=0;r<4;r++){
                    const int gi = i0 + w*16 + lk4*4 + r;
                    #pragma unroll
                    for (int n=0;n<4;n++)
                        if (j0 + n*16 + lr > gi) s2[n][r] = -INFINITY;
                }
            }
            #pragma unroll
            for (int r=0;r<4;r++){
                float p0 = __builtin_amdgcn_exp2f(s2[0][r]);
                float p1 = __builtin_amdgcn_exp2f(s2[1][r]);
                float p2 = __builtin_amdgcn_exp2f(s2[2][r]);
                float p3 = __builtin_amdgcn_exp2f(s2[3][r]);
                l_r[r] += (p0+p1)+(p2+p3);
                unsigned int u01 = cvt_pk_bf16(p0, p1);
                unsigned int u23 = cvt_pk_bf16(p2, p3);
                const int li = w*16 + lk4*4 + r;
                const int ro = li*64 + (lr&7);
                p_lds[ro + (((0 + (lr>>3)) ^ (li&7))<<3)] = (unsigned short)u01;
                p_lds[ro + (((2 + (lr>>3)) ^ (li&7))<<3)] = (unsigned short)(u01>>16);
                p_lds[ro + (((4 + (lr>>3)) ^ (li&7))<<3)] = (unsigned short)u23;
                p_lds[ro + (((6 + (lr>>3)) ^ (li&7))<<3)] = (unsigned short)(u23>>16);
            }

            // O += P V
            __builtin_amdgcn_s_setprio(1);
            #pragma unroll
            for (int kk=0;kk<2;kk++){
                const int sco = ((kk*4+lk4) ^ (lr&7)) << 3;
                short8 pf = *(const short8*)(&p_lds[(w*16+lr)*64 + sco]);
                #pragma unroll
                for (int n=0;n<4;n++){
                    short8 vf = *(const short8*)(&vt_lds[(n*16+lr)*64 + sco]);
                    o_acc[n] = __builtin_amdgcn_mfma_f32_16x16x32_bf16(pf, vf, o_acc[n], 0,0,0);
                }
            }
            __builtin_amdgcn_s_setprio(0);
            __syncthreads();                        // drains K/Er(t+1); VT/p readers done
        }

        // segment epilogue
        #pragma unroll
        for (int r=0;r<4;r++){
            float l = l_r[r];
            #pragma unroll
            for (int msk=1; msk<16; msk<<=1) l += __shfl_xor(l, msk);
            l_r[r] = 1.0f / l;
        }
        const int b_ = bh >> 4, h = bh & 15;
        #pragma unroll
        for (int n=0;n<4;n++)
            #pragma unroll
            for (int r=0;r<4;r++){
                int li = w*16 + lk4*4 + r;
                int d = n*16 + lr;
                out[(b_*SS + i0 + li)*DM + h*DH + d] = o_acc[n][r] * l_r[r];
            }
    }
}

extern "C" void kernel_launch(void* const* d_in, const int* in_sizes, int n_in,
                              void* d_out, int out_size, void* d_ws, size_t ws_size,
                              hipStream_t stream)
{
    const float* x  = (const float*)d_in[0];
    const float* Wq = (const float*)d_in[1];
    const float* bq = (const float*)d_in[2];
    const float* Wk = (const float*)d_in[3];
    const float* bk = (const float*)d_in[4];
    const float* Wv = (const float*)d_in[5];
    const float* bv = (const float*)d_in[6];
    const float* Er = (const float*)d_in[7];
    float* out = (float*)d_out;
    char* ws = (char*)d_ws;
    unsigned short* xb  = (unsigned short*)(ws);              // 8 MB   x bf16 [4096][1024]; later reused as VT
    unsigned short* wT  = (unsigned short*)(ws + 8388608);    // 6 MB   W^T bf16 [3072][1024]
    unsigned short* erb = (unsigned short*)(ws + 14680064);   // 144 KB Er bf16 [1152][64] (128 zero rows)
    unsigned short* Qb  = (unsigned short*)(ws + 14827520);   // 8 MB   Q bf16 [bh][s][d] (pre-scaled C2)
    unsigned short* Kb  = (unsigned short*)(ws + 23216128);   // 8 MB   K bf16 [bh][s][d]
    unsigned short* Vb  = (unsigned short*)(ws + 31604736);   // 8 MB   V bf16 [bh][s][d]
    unsigned short* VTb = xb;                                 // V^T bf16 [bh][d][s] (aliases xb, dead after gemm)

    cast_f32_bf16_k<<<4096, 256, 0, stream>>>(x, xb);
    cast_f32_bf16_k<<<64, 256, 0, stream>>>(Er, erb);
    hipMemsetAsync(erb + 1024*DH, 0, 128*DH*sizeof(unsigned short), stream);
    transpose_cast_w_k<<<dim3(32,32,3), dim3(32,8), 0, stream>>>(Wq, Wk, Wv, wT);
    gemm_qkv_k<<<dim3(24,32), 256, 0, stream>>>(xb, wT, bq, bk, bv, Qb, Kb, Vb);
    transpose_v_k<<<dim3(64,16), 256, 0, stream>>>(Vb, VTb);
    attn_k<<<dim3(64,8), 256, 0, stream>>>(Qb, Kb, VTb, erb, out);
}